// Round 1
// baseline (3609.018 us; speedup 1.0000x reference)
//
#include <hip/hip_runtime.h>
#include <float.h>
#include <math.h>

#define HIDDEN 256
#define HALF_H 128
#define T1 16   // agents per block in scores_kernel
#define T5 16   // teams per block in proj_kernel

__device__ __forceinline__ void atomicMaxFloat(float* addr, float val) {
    // Standard monotonic-bits trick: nonneg floats order as signed ints,
    // negative floats order inversely as unsigned ints.
    if (val >= 0.0f) atomicMax((int*)addr, __float_as_int(val));
    else             atomicMin((unsigned int*)addr, __float_as_uint(val));
}

__global__ void init_teams_kernel(float* __restrict__ seg_max,
                                  float* __restrict__ denom, int n_teams) {
    int i = blockIdx.x * blockDim.x + threadIdx.x;
    if (i < n_teams) { seg_max[i] = -FLT_MAX; denom[i] = 0.0f; }
}

// h = tanh(A@W1 + b1); scores = h@W2 + b2; atomicMax into seg_max.
// blockDim = 128: thread j owns column j of W1/h. 16 agents per block,
// agent-row loads are wave-uniform -> scalar (SMEM) loads.
__global__ void scores_kernel(const float* __restrict__ A,
                              const float* __restrict__ W1,
                              const float* __restrict__ b1,
                              const float* __restrict__ W2,
                              const float* __restrict__ b2,
                              const int* __restrict__ team_idx,
                              float* __restrict__ scores,
                              float* __restrict__ seg_max,
                              int n_agents) {
    const int j    = threadIdx.x;        // 0..127
    const int lane = threadIdx.x & 63;
    const int wid  = threadIdx.x >> 6;   // 0..1
    const long i0  = (long)blockIdx.x * T1;

    long rows[T1];
#pragma unroll
    for (int t = 0; t < T1; ++t) {
        long i = i0 + t;
        if (i >= n_agents) i = i0;       // clamp to a row this block owns (reads only)
        rows[t] = i * HIDDEN;
    }

    float acc[T1];
#pragma unroll
    for (int t = 0; t < T1; ++t) acc[t] = 0.0f;

#pragma unroll 4
    for (int k = 0; k < HIDDEN; ++k) {
        float w = W1[k * HALF_H + j];    // coalesced across j, L2-resident
#pragma unroll
        for (int t = 0; t < T1; ++t)
            acc[t] += A[rows[t] + k] * w;  // uniform index -> s_load
    }

    const float w2  = W2[j];
    const float b1j = b1[j];
    const float b2v = b2[0];

    __shared__ float sred[2][T1];
#pragma unroll
    for (int t = 0; t < T1; ++t) {
        float v = tanhf(acc[t] + b1j) * w2;
#pragma unroll
        for (int off = 32; off > 0; off >>= 1)
            v += __shfl_down(v, off, 64);
        if (lane == 0) sred[wid][t] = v;
    }
    __syncthreads();
    if (threadIdx.x < T1) {
        int t = threadIdx.x;
        long i = i0 + t;
        if (i < n_agents) {
            float s = sred[0][t] + sred[1][t] + b2v;
            scores[i] = s;
            atomicMaxFloat(&seg_max[team_idx[i]], s);
        }
    }
}

__global__ void exp_kernel(const int* __restrict__ team_idx,
                           const float* __restrict__ seg_max,
                           float* __restrict__ scores,
                           float* __restrict__ denom, int n_agents) {
    int i = blockIdx.x * blockDim.x + threadIdx.x;
    if (i < n_agents) {
        int t = team_idx[i];
        float e = expf(scores[i] - seg_max[t]);
        scores[i] = e;   // overwrite in place with exp_s
        atomicAdd(&denom[t], e);
    }
}

// attn = e/denom -> out_attn; out_team[t] += attn * agent_row (atomic scatter).
// One 64-lane wave per agent; lane reads float4 of the row.
__global__ void accum_kernel(const float* __restrict__ A,
                             const float* __restrict__ e,
                             const float* __restrict__ denom,
                             const int* __restrict__ team_idx,
                             float* __restrict__ out_team,
                             float* __restrict__ out_attn,
                             int n_agents) {
    int gw   = (blockIdx.x * blockDim.x + threadIdx.x) >> 6;
    int lane = threadIdx.x & 63;
    if (gw >= n_agents) return;
    int t = team_idx[gw];
    float a = e[gw] / denom[t];
    if (lane == 0) out_attn[gw] = a;
    float4 v = ((const float4*)(A + (long)gw * HIDDEN))[lane];
    float* Trow = out_team + (long)t * HIDDEN + lane * 4;
    atomicAdd(Trow + 0, a * v.x);
    atomicAdd(Trow + 1, a * v.y);
    atomicAdd(Trow + 2, a * v.z);
    atomicAdd(Trow + 3, a * v.w);
}

// out_team = relu(out_team @ Wo + bo), in place. blockDim = 256 (thread j =
// output column), 16 teams/block register-blocked; team-row loads uniform ->
// s_load. __syncthreads separates all reads from any write (block owns its rows).
__global__ void proj_kernel(const float* __restrict__ Wo,
                            const float* __restrict__ bo,
                            float* __restrict__ out_team, int n_teams) {
    const int j   = threadIdx.x;         // 0..255
    const long t0 = (long)blockIdx.x * T5;

    long rows[T5];
#pragma unroll
    for (int t = 0; t < T5; ++t) {
        long tt = t0 + t;
        if (tt >= n_teams) tt = t0;      // clamp to own first row (no cross-block race)
        rows[t] = tt * HIDDEN;
    }

    float acc[T5];
#pragma unroll
    for (int t = 0; t < T5; ++t) acc[t] = 0.0f;

#pragma unroll 4
    for (int k = 0; k < HIDDEN; ++k) {
        float w = Wo[k * HIDDEN + j];    // coalesced across j, L2-resident
#pragma unroll
        for (int t = 0; t < T5; ++t)
            acc[t] += out_team[rows[t] + k] * w;   // uniform -> s_load
    }

    const float bj = bo[j];
    __syncthreads();                      // all reads complete before any write
#pragma unroll
    for (int t = 0; t < T5; ++t) {
        long tt = t0 + t;
        if (tt < n_teams) {
            float v = acc[t] + bj;
            out_team[tt * HIDDEN + j] = v > 0.0f ? v : 0.0f;
        }
    }
}

extern "C" void kernel_launch(void* const* d_in, const int* in_sizes, int n_in,
                              void* d_out, int out_size, void* d_ws, size_t ws_size,
                              hipStream_t stream) {
    const float* agent_h  = (const float*)d_in[0];
    const int*   team_idx = (const int*)d_in[1];
    // d_in[2] = n_teams scalar on device; derive on host from sizes instead.
    const float* W1 = (const float*)d_in[3];
    const float* b1 = (const float*)d_in[4];
    const float* W2 = (const float*)d_in[5];
    const float* b2 = (const float*)d_in[6];
    const float* Wo = (const float*)d_in[7];
    const float* bo = (const float*)d_in[8];

    const int n_agents = in_sizes[0] / HIDDEN;                 // 400000
    const int n_teams  = (out_size - n_agents) / HIDDEN;       // 100000

    float* out_team = (float*)d_out;                           // [n_teams,256]
    float* out_attn = (float*)d_out + (long)n_teams * HIDDEN;  // [n_agents]

    float* scores  = (float*)d_ws;            // n_agents
    float* seg_max = scores + n_agents;       // n_teams
    float* denom   = seg_max + n_teams;       // n_teams

    hipMemsetAsync(out_team, 0, (size_t)n_teams * HIDDEN * sizeof(float), stream);
    init_teams_kernel<<<(n_teams + 255) / 256, 256, 0, stream>>>(seg_max, denom, n_teams);

    scores_kernel<<<(n_agents + T1 - 1) / T1, 128, 0, stream>>>(
        agent_h, W1, b1, W2, b2, team_idx, scores, seg_max, n_agents);

    exp_kernel<<<(n_agents + 255) / 256, 256, 0, stream>>>(
        team_idx, seg_max, scores, denom, n_agents);

    accum_kernel<<<(n_agents + 3) / 4, 256, 0, stream>>>(
        agent_h, scores, denom, team_idx, out_team, out_attn, n_agents);

    proj_kernel<<<(n_teams + T5 - 1) / T5, 256, 0, stream>>>(
        Wo, bo, out_team, n_teams);
}

// Round 2
// 2692.443 us; speedup vs baseline: 1.3404x; 1.3404x over previous
//
#include <hip/hip_runtime.h>
#include <float.h>
#include <math.h>

#define HIDDEN 256
#define HALF_H 128
#define SB_AG 32   // agents per block in scores_kernel
#define PB    16   // teams per block in proj_kernel

__device__ __forceinline__ void atomicMaxFloat(float* addr, float val) {
    if (val >= 0.0f) atomicMax((int*)addr, __float_as_int(val));
    else             atomicMin((unsigned int*)addr, __float_as_uint(val));
}

// overflow-safe fast tanh using hw v_exp_f32
__device__ __forceinline__ float fast_tanh(float x) {
    float ax = fabsf(x);
    float e  = __expf(-2.0f * ax);          // in (0,1], never overflows
    float r  = (1.0f - e) / (1.0f + e);
    return copysignf(r, x);
}

__global__ void init_teams_kernel(float* __restrict__ seg_max,
                                  float* __restrict__ denom, int n_teams) {
    int i = blockIdx.x * blockDim.x + threadIdx.x;
    if (i < n_teams) { seg_max[i] = -FLT_MAX; denom[i] = 0.0f; }
}

// scores = tanh(A@W1+b1)@W2 + b2 ; atomicMax into seg_max.
// block=256. LDS-staged A tile (32x256 fp32 = 32KB, coalesced float4 loads).
// thread (j=tid&127, g=tid>>7) owns W1 column j for agents g*16..g*16+15.
// LDS reads are wave-broadcast ds_read_b128 (all lanes same address -> free).
__global__ void scores_kernel(const float* __restrict__ A,
                              const float* __restrict__ W1,
                              const float* __restrict__ b1,
                              const float* __restrict__ W2,
                              const float* __restrict__ b2,
                              const int* __restrict__ team_idx,
                              float* __restrict__ scores,
                              float* __restrict__ seg_max,
                              int n_agents) {
    __shared__ float sA[SB_AG][HIDDEN];          // 32 KB
    __shared__ float sred[4][16];

    const int  tid = threadIdx.x;
    const long i0  = (long)blockIdx.x * SB_AG;

    // stage tile: 32 rows x 64 float4 = 2048 float4; 8 per thread, coalesced
#pragma unroll
    for (int p = 0; p < 8; ++p) {
        int idx = p * 256 + tid;
        int r = idx >> 6, c = idx & 63;
        long row = i0 + r;
        if (row >= n_agents) row = n_agents - 1;   // clamp (reads only)
        ((float4*)&sA[r][0])[c] = ((const float4*)(A + row * HIDDEN))[c];
    }
    __syncthreads();

    const int j = tid & 127;     // W1 column
    const int g = tid >> 7;      // agent half-group

    float acc[16];
#pragma unroll
    for (int t = 0; t < 16; ++t) acc[t] = 0.0f;

    for (int k = 0; k < HIDDEN; k += 4) {
        float4 w;
        w.x = W1[(k + 0) * HALF_H + j];
        w.y = W1[(k + 1) * HALF_H + j];
        w.z = W1[(k + 2) * HALF_H + j];
        w.w = W1[(k + 3) * HALF_H + j];
#pragma unroll
        for (int t = 0; t < 16; ++t) {
            float4 a = *((const float4*)&sA[g * 16 + t][k]);   // broadcast
            acc[t] += a.x * w.x + a.y * w.y + a.z * w.z + a.w * w.w;
        }
    }

    const float w2  = W2[j];
    const float b1j = b1[j];
    const int   lane = tid & 63;
    const int   wave = tid >> 6;     // 0..3; waves {2g, 2g+1} cover group g

#pragma unroll
    for (int t = 0; t < 16; ++t) {
        float v = fast_tanh(acc[t] + b1j) * w2;
#pragma unroll
        for (int off = 32; off > 0; off >>= 1)
            v += __shfl_down(v, off, 64);
        if (lane == 0) sred[wave][t] = v;
    }
    __syncthreads();

    if (tid < SB_AG) {
        int a  = tid;
        int g2 = a >> 4, t = a & 15;
        long i = i0 + a;
        if (i < n_agents) {
            float s = sred[2 * g2][t] + sred[2 * g2 + 1][t] + b2[0];
            scores[i] = s;
            atomicMaxFloat(&seg_max[team_idx[i]], s);
        }
    }
}

__global__ void exp_kernel(const int* __restrict__ team_idx,
                           const float* __restrict__ seg_max,
                           float* __restrict__ scores,
                           float* __restrict__ denom, int n_agents) {
    int i = blockIdx.x * blockDim.x + threadIdx.x;
    if (i < n_agents) {
        int t = team_idx[i];
        float e = __expf(scores[i] - seg_max[t]);
        scores[i] = e;
        atomicAdd(&denom[t], e);
    }
}

// attn = e/denom -> out_attn; out_team[t] += attn * agent_row (atomic scatter).
__global__ void accum_kernel(const float* __restrict__ A,
                             const float* __restrict__ e,
                             const float* __restrict__ denom,
                             const int* __restrict__ team_idx,
                             float* __restrict__ out_team,
                             float* __restrict__ out_attn,
                             int n_agents) {
    int gw   = (blockIdx.x * blockDim.x + threadIdx.x) >> 6;
    int lane = threadIdx.x & 63;
    if (gw >= n_agents) return;
    int t = team_idx[gw];
    float a = e[gw] / denom[t];
    if (lane == 0) out_attn[gw] = a;
    float4 v = ((const float4*)(A + (long)gw * HIDDEN))[lane];
    float* Trow = out_team + (long)t * HIDDEN + lane * 4;
    atomicAdd(Trow + 0, a * v.x);
    atomicAdd(Trow + 1, a * v.y);
    atomicAdd(Trow + 2, a * v.z);
    atomicAdd(Trow + 3, a * v.w);
}

// out_team = relu(out_team @ Wo + bo), in place. LDS-staged team tile.
// block=256, thread j = output column, 16 teams register-blocked.
__global__ void proj_kernel(const float* __restrict__ Wo,
                            const float* __restrict__ bo,
                            float* __restrict__ out_team, int n_teams) {
    __shared__ float sT[PB][HIDDEN];             // 16 KB

    const int  j  = threadIdx.x;                 // 0..255
    const long t0 = (long)blockIdx.x * PB;

    // stage tile: 16 rows x 64 float4 = 1024 float4; 4 per thread, coalesced
#pragma unroll
    for (int p = 0; p < 4; ++p) {
        int idx = p * 256 + j;
        int r = idx >> 6, c = idx & 63;
        long row = t0 + r;
        if (row >= n_teams) row = n_teams - 1;
        ((float4*)&sT[r][0])[c] = ((const float4*)(out_team + row * HIDDEN))[c];
    }
    __syncthreads();

    float acc[PB];
#pragma unroll
    for (int t = 0; t < PB; ++t) acc[t] = 0.0f;

    for (int k = 0; k < HIDDEN; k += 4) {
        float4 w;
        w.x = Wo[(k + 0) * HIDDEN + j];
        w.y = Wo[(k + 1) * HIDDEN + j];
        w.z = Wo[(k + 2) * HIDDEN + j];
        w.w = Wo[(k + 3) * HIDDEN + j];
#pragma unroll
        for (int t = 0; t < PB; ++t) {
            float4 a = *((const float4*)&sT[t][k]);     // broadcast
            acc[t] += a.x * w.x + a.y * w.y + a.z * w.z + a.w * w.w;
        }
    }

    const float bj = bo[j];
#pragma unroll
    for (int t = 0; t < PB; ++t) {
        long tt = t0 + t;
        if (tt < n_teams) {
            float v = acc[t] + bj;
            out_team[tt * HIDDEN + j] = v > 0.0f ? v : 0.0f;
        }
    }
}

extern "C" void kernel_launch(void* const* d_in, const int* in_sizes, int n_in,
                              void* d_out, int out_size, void* d_ws, size_t ws_size,
                              hipStream_t stream) {
    const float* agent_h  = (const float*)d_in[0];
    const int*   team_idx = (const int*)d_in[1];
    const float* W1 = (const float*)d_in[3];
    const float* b1 = (const float*)d_in[4];
    const float* W2 = (const float*)d_in[5];
    const float* b2 = (const float*)d_in[6];
    const float* Wo = (const float*)d_in[7];
    const float* bo = (const float*)d_in[8];

    const int n_agents = in_sizes[0] / HIDDEN;                 // 400000
    const int n_teams  = (out_size - n_agents) / HIDDEN;       // 100000

    float* out_team = (float*)d_out;                           // [n_teams,256]
    float* out_attn = (float*)d_out + (long)n_teams * HIDDEN;  // [n_agents]

    float* scores  = (float*)d_ws;            // n_agents
    float* seg_max = scores + n_agents;       // n_teams
    float* denom   = seg_max + n_teams;       // n_teams

    hipMemsetAsync(out_team, 0, (size_t)n_teams * HIDDEN * sizeof(float), stream);
    init_teams_kernel<<<(n_teams + 255) / 256, 256, 0, stream>>>(seg_max, denom, n_teams);

    scores_kernel<<<(n_agents + SB_AG - 1) / SB_AG, 256, 0, stream>>>(
        agent_h, W1, b1, W2, b2, team_idx, scores, seg_max, n_agents);

    exp_kernel<<<(n_agents + 255) / 256, 256, 0, stream>>>(
        team_idx, seg_max, scores, denom, n_agents);

    accum_kernel<<<(n_agents + 3) / 4, 256, 0, stream>>>(
        agent_h, scores, denom, team_idx, out_team, out_attn, n_agents);

    proj_kernel<<<(n_teams + PB - 1) / PB, 256, 0, stream>>>(
        Wo, bo, out_team, n_teams);
}